// Round 11
// baseline (116.266 us; speedup 1.0000x reference)
//
#include <hip/hip_runtime.h>
#include <hip/hip_bf16.h>

// Attention block: y = proj(softmax(QK^T/sqrt(d)) V), QKV from one GEMM.
// B=8, S=1024, DIM=768, H=12, HD=64.  bf16 MFMA w/ fp32 accum throughout.

typedef __attribute__((ext_vector_type(4)))  float f32x4;
typedef __attribute__((ext_vector_type(16))) float f32x16;
typedef __attribute__((ext_vector_type(8)))  short short8;
typedef __attribute__((ext_vector_type(4)))  short short4v;
typedef __attribute__((ext_vector_type(2)))  unsigned int uint2v;
typedef __attribute__((ext_vector_type(4)))  unsigned int uint4v;

__device__ __forceinline__ unsigned short f2bf_hw(float f) {
  return __builtin_bit_cast(unsigned short, __float2bfloat16(f));       // hw cvt, RNE
}
__device__ __forceinline__ unsigned int pk2bf(float a, float b) {
  return (unsigned int)f2bf_hw(a) | ((unsigned int)f2bf_hw(b) << 16);   // compiler packs
}

#define MFMA16(a, b, c) __builtin_amdgcn_mfma_f32_16x16x32_bf16((a), (b), (c), 0, 0, 0)
#define MFMA32(a, b, c) __builtin_amdgcn_mfma_f32_32x32x16_bf16((a), (b), (c), 0, 0, 0)

// Q pre-scale: 1/sqrt(64) * log2(e)  -> QK^T scores land in exp2 domain
#define QSCALE 0.18033688011112042f

__device__ __forceinline__ void gload_lds16(const unsigned short* g, char* lds) {
  __builtin_amdgcn_global_load_lds(
      (const __attribute__((address_space(1))) unsigned int*)g,
      (__attribute__((address_space(3))) unsigned int*)lds, 16, 0, 0);
}

// ---------------------------------------------------------------------------
// fp32 -> bf16 for x, qkv_w, proj_w in one launch (sizes in f32x4 units).
// ---------------------------------------------------------------------------
__global__ __launch_bounds__(256)
void cvt3(const float* __restrict__ a, unsigned short* __restrict__ da, int na,
          const float* __restrict__ b, unsigned short* __restrict__ db, int nb,
          const float* __restrict__ c, unsigned short* __restrict__ dc)
{
  int i = blockIdx.x * 256 + threadIdx.x;
  const float* s; unsigned short* d;
  if (i < na)           { s = a; d = da; }
  else if (i < na + nb) { s = b; d = db; i -= na; }
  else                  { s = c; d = dc; i -= na + nb; }
  f32x4 v = ((const f32x4*)s)[i];
  short4v h;
  h[0] = (short)f2bf_hw(v[0]); h[1] = (short)f2bf_hw(v[1]);
  h[2] = (short)f2bf_hw(v[2]); h[3] = (short)f2bf_hw(v[3]);
  ((short4v*)d)[i] = h;
}

// ---------------------------------------------------------------------------
// BT-GEMM (unchanged from R6): both operands bf16 via global_load_lds,
// double-buffered, counted vmcnt(8). 128x128x64, 4 waves.
// ---------------------------------------------------------------------------
template<int EPI>
__global__ __launch_bounds__(256)
void gemm_bt(const unsigned short* __restrict__ A, const unsigned short* __restrict__ Wb,
             const float* __restrict__ bias,
             unsigned short* __restrict__ Qt, unsigned short* __restrict__ Kt,
             unsigned short* __restrict__ Vt, float* __restrict__ Out)
{
  __shared__ char lds[65536];              // [buf][A 16K | W 16K]
  const int tid = threadIdx.x;
  const int w = tid >> 6, l = tid & 63, lr = l & 15, lg = l >> 4;
  const int wr = w >> 1, wc = w & 1;
  const int m0 = blockIdx.x * 128, n0 = blockIdx.y * 128;
  f32x4 acc[4][4] = {};

  const int srow = tid >> 3;
  const int cb   = ((tid & 7) << 4) ^ ((srow & 7) << 4);
  const unsigned short* pA = A  + (size_t)(m0 + srow) * 768 + (cb >> 1);
  const unsigned short* pW = Wb + (size_t)(n0 + srow) * 768 + (cb >> 1);
  char* const ldsA = lds + tid * 16;
  char* const ldsW = lds + 16384 + tid * 16;

  #pragma unroll
  for (int c = 0; c < 4; ++c) gload_lds16(pA + c * 32 * 768, ldsA + c * 4096);
  #pragma unroll
  for (int c = 0; c < 4; ++c) gload_lds16(pW + c * 32 * 768, ldsW + c * 4096);
  pA += 64; pW += 64;

  for (int kt = 0; kt < 12; ++kt) {
    if (kt < 11) {
      const int nb = ((kt + 1) & 1) * 32768;
      #pragma unroll
      for (int c = 0; c < 4; ++c) gload_lds16(pA + c * 32 * 768, ldsA + nb + c * 4096);
      #pragma unroll
      for (int c = 0; c < 4; ++c) gload_lds16(pW + c * 32 * 768, ldsW + nb + c * 4096);
      pA += 64; pW += 64;
      asm volatile("s_waitcnt vmcnt(8)" ::: "memory");
    } else {
      asm volatile("s_waitcnt vmcnt(0)" ::: "memory");
    }
    __builtin_amdgcn_s_barrier();
    __builtin_amdgcn_sched_barrier(0);

    const char* Ab = lds + (kt & 1) * 32768;
    const char* Bb = Ab + 16384;
    #pragma unroll
    for (int kc = 0; kc < 2; ++kc) {
      short8 af[4], bfr[4];
      #pragma unroll
      for (int mf = 0; mf < 4; ++mf) {
        const int row = wr * 64 + mf * 16 + lr;
        af[mf] = *(const short8*)(Ab + row * 128 +
                                  ((kc * 64 + lg * 16) ^ ((row & 7) << 4)));
      }
      #pragma unroll
      for (int nf = 0; nf < 4; ++nf) {
        const int row = wc * 64 + nf * 16 + lr;
        bfr[nf] = *(const short8*)(Bb + row * 128 +
                                   ((kc * 64 + lg * 16) ^ ((row & 7) << 4)));
      }
      #pragma unroll
      for (int mf = 0; mf < 4; ++mf)
        #pragma unroll
        for (int nf = 0; nf < 4; ++nf)
          acc[mf][nf] = MFMA16(af[mf], bfr[nf], acc[mf][nf]);
    }
    __builtin_amdgcn_s_barrier();
  }

  if constexpr (EPI == 0) {
    const int tt = blockIdx.y / 6;         // 0=Q 1=K 2=V
    const int h = (blockIdx.y % 6) * 2 + wc;
    #pragma unroll
    for (int nf = 0; nf < 4; ++nf) {
      const int dh = nf * 16 + lr;
      const float bv = bias[n0 + wc * 64 + dh];
      #pragma unroll
      for (int mf = 0; mf < 4; ++mf) {
        const int mb = m0 + wr * 64 + mf * 16 + lg * 4;
        const int b_ = mb >> 10, s_ = mb & 1023;
        f32x4 c = acc[mf][nf];
        if (tt == 0) {
          unsigned short* p = Qt + ((b_ * 12 + h) * 1024 + s_) * 64 + dh;
          #pragma unroll
          for (int j = 0; j < 4; ++j) p[j * 64] = f2bf_hw((c[j] + bv) * QSCALE);
        } else if (tt == 1) {
          unsigned short* p = Kt + ((b_ * 12 + h) * 1024 + s_) * 64 + dh;
          #pragma unroll
          for (int j = 0; j < 4; ++j) p[j * 64] = f2bf_hw(c[j] + bv);
        } else {
          short4v pk;
          #pragma unroll
          for (int j = 0; j < 4; ++j) pk[j] = (short)f2bf_hw(c[j] + bv);
          *(short4v*)(Vt + ((b_ * 12 + h) * 64 + dh) * 1024 + s_) = pk;  // V^T (d,s)
        }
      }
    }
  } else {
    #pragma unroll
    for (int nf = 0; nf < 4; ++nf) {
      const int e = n0 + wc * 64 + nf * 16 + lr;
      const float bv = bias[e];
      #pragma unroll
      for (int mf = 0; mf < 4; ++mf) {
        const int mb = m0 + wr * 64 + mf * 16 + lg * 4;
        #pragma unroll
        for (int j = 0; j < 4; ++j)
          Out[(size_t)(mb + j) * 768 + e] = acc[mf][nf][j] + bv;
      }
    }
  }
}

// ---------------------------------------------------------------------------
// Flash attention fwd v6 — v5 + counted-vmcnt double buffer (T4).
// Per iter: {issue 4 stage loads (t+1) -> vmcnt(4) -> s_barrier -> compute
// -> s_barrier}.  No vmcnt(0) drain in-loop: prefetch stays in flight across
// the barrier (the __syncthreads in v5 drained it -> serial L2 latency).
// Grid 768 = 96 heads x 8 q-tiles(128).  4 waves x 32 q-rows, in-reg P,
// no max tracking (scores bounded; softmax shift-invariant).  LDS 32 KB.
// C layout (m74/m101): col=lane&31, row=(reg&3)+8*(reg>>2)+4*(lane>>5).
// ---------------------------------------------------------------------------
__global__ __launch_bounds__(256, 4)
void attn_fwd(const unsigned short* __restrict__ Qt,
              const unsigned short* __restrict__ Kt,
              const unsigned short* __restrict__ Vt,
              unsigned short* __restrict__ AO)
{
  __shared__ char lds[32768];
  char* Ks = lds;                 // 2 x 8192: [64 key rows][128 B] swz
  char* Vs = lds + 16384;         // 2 x 8192: [64 d rows][128 B] swz

  const int bid = blockIdx.x;
  const int bh = bid % 96, qt = bid / 96;       // same head -> same XCD (96%8==0)
  const int tid = threadIdx.x, w = tid >> 6, l = tid & 63;
  const int l31 = l & 31, hi = l >> 5;
  const unsigned short* Qh = Qt + bh * 65536;
  const unsigned short* Kh = Kt + bh * 65536;
  const unsigned short* Vh = Vt + bh * 65536;   // (d, s) layout
  const int b_ = bh / 12, h = bh % 12;

  const int srow = tid >> 3;                    // staging rows 0..31 (+32)
  const int cb   = ((tid & 7) << 4) ^ ((srow & 7) << 4);
  char* const ldsK = Ks + tid * 16;
  char* const ldsV = Vs + tid * 16;

  // Q B-frags (col=q=lane&31, k=d=hi*8+e), held in regs all kernel
  const int q0 = qt * 128 + w * 32;
  const unsigned short* qp = Qh + (size_t)(q0 + l31) * 64 + hi * 8;
  short8 bq[4];
  #pragma unroll
  for (int kk = 0; kk < 4; ++kk) bq[kk] = *(const short8*)(qp + kk * 16);

  // prologue: stage KV tile 0 into buf 0 (landing guarded by loop-top wait)
  #pragma unroll
  for (int c = 0; c < 2; ++c)
    gload_lds16(Kh + (size_t)(srow + c * 32) * 64 + (cb >> 1), ldsK + c * 4096);
  #pragma unroll
  for (int c = 0; c < 2; ++c)
    gload_lds16(Vh + (size_t)(srow + c * 32) * 1024 + (cb >> 1), ldsV + c * 4096);

  float lsum = 0.f;                // per-lane q-col = q0 + l31
  f32x16 o0 = {}, o1 = {};         // O^T: col q, rows d (dblk 0: 0-31, 1: 32-63)

  for (int t = 0; t < 16; ++t) {
    const int cur = t & 1;
    // ---- stage next KV tile (async; stays in flight across the barrier) ----
    if (t < 15) {
      const int nk = (t + 1) * 64;
      const int nb = (cur ^ 1) * 8192;
      #pragma unroll
      for (int c = 0; c < 2; ++c)
        gload_lds16(Kh + (size_t)(nk + srow + c * 32) * 64 + (cb >> 1),
                    ldsK + nb + c * 4096);
      #pragma unroll
      for (int c = 0; c < 2; ++c)
        gload_lds16(Vh + (size_t)(srow + c * 32) * 1024 + nk + (cb >> 1),
                    ldsV + nb + c * 4096);
      asm volatile("s_waitcnt vmcnt(4)" ::: "memory");  // own tile-t loads landed
    } else {
      asm volatile("s_waitcnt vmcnt(0)" ::: "memory");
    }
    __builtin_amdgcn_s_barrier();                       // all waves' tile-t landed
    __builtin_amdgcn_sched_barrier(0);

    const char* Kb = Ks + cur * 8192;
    const char* Vb = Vs + cur * 8192;

    #pragma unroll
    for (int kb = 0; kb < 2; ++kb) {
      // ---- S^T = K Q^T (A = K[32 keys][16 d], B = Q^T) ----
      const int krow = kb * 32 + l31;
      const char* kbase = Kb + krow * 128;
      const int kswz = (krow & 7) << 4;
      f32x16 s = {};
      __builtin_amdgcn_s_setprio(1);
      #pragma unroll
      for (int kk = 0; kk < 4; ++kk) {
        short8 ka = *(const short8*)(kbase + ((kk * 32 + hi * 16) ^ kswz));
        s = MFMA32(ka, bq[kk], s);
      }
      __builtin_amdgcn_s_setprio(0);

      // ---- softmax numerator: P = exp2(s) directly (no max, shift-free) ----
      float ts = 0.f;
      unsigned int pk_[8];
      #pragma unroll
      for (int i = 0; i < 8; ++i) {
        const float pa = exp2f(s[2 * i]);
        const float pb = exp2f(s[2 * i + 1]);
        ts += pa + pb;
        pk_[i] = pk2bf(pa, pb);
      }
      ts += __shfl_xor(ts, 32);
      lsum += ts;

      // ---- build PV B-frags in regs (keys kb*32+0..15 and +16..31) ----
      const unsigned int x0 = __shfl_xor(pk_[0], 32), x1 = __shfl_xor(pk_[1], 32);
      const unsigned int x2 = __shfl_xor(pk_[2], 32), x3 = __shfl_xor(pk_[3], 32);
      const unsigned int x4 = __shfl_xor(pk_[4], 32), x5 = __shfl_xor(pk_[5], 32);
      const unsigned int x6 = __shfl_xor(pk_[6], 32), x7 = __shfl_xor(pk_[7], 32);
      uint4v b0v, b1v;
      b0v[0] = hi ? x2 : pk_[0];  b0v[1] = hi ? x3 : pk_[1];
      b0v[2] = hi ? pk_[2] : x0;  b0v[3] = hi ? pk_[3] : x1;
      b1v[0] = hi ? x6 : pk_[4];  b1v[1] = hi ? x7 : pk_[5];
      b1v[2] = hi ? pk_[6] : x4;  b1v[3] = hi ? pk_[7] : x5;
      const short8 pb0 = __builtin_bit_cast(short8, b0v);
      const short8 pb1 = __builtin_bit_cast(short8, b1v);

      // ---- O^T += V^T P^T (A = V^T[d][16 keys], B = P[16 keys][q]) ----
      const int vswz = (l31 & 7) << 4;      // (row&7) same for both dblks
      __builtin_amdgcn_s_setprio(1);
      #pragma unroll
      for (int kk = 0; kk < 2; ++kk) {
        const short8 pbk = kk ? pb1 : pb0;
        const int koff = kb * 64 + kk * 32 + hi * 16;
        short8 va0 = *(const short8*)(Vb + l31 * 128 + (koff ^ vswz));
        o0 = MFMA32(va0, pbk, o0);
        short8 va1 = *(const short8*)(Vb + (32 + l31) * 128 + (koff ^ vswz));
        o1 = MFMA32(va1, pbk, o1);
      }
      __builtin_amdgcn_s_setprio(0);
    }

    __builtin_amdgcn_s_barrier();   // reads of buf cur done before overwrite
  }

  // ---- epilogue: lane-local normalize; q fixed per lane, d contiguous ----
  const float inv = 1.f / lsum;
  unsigned short* aop = AO + ((size_t)(b_ * 1024 + q0 + l31)) * 768 + h * 64;
  #pragma unroll
  for (int g = 0; g < 4; ++g) {
    uint2v s0, s1;
    s0[0] = pk2bf(o0[4 * g] * inv,     o0[4 * g + 1] * inv);
    s0[1] = pk2bf(o0[4 * g + 2] * inv, o0[4 * g + 3] * inv);
    *(uint2v*)(aop + g * 8 + 4 * hi) = s0;
    s1[0] = pk2bf(o1[4 * g] * inv,     o1[4 * g + 1] * inv);
    s1[1] = pk2bf(o1[4 * g + 2] * inv, o1[4 * g + 3] * inv);
    *(uint2v*)(aop + 32 + g * 8 + 4 * hi) = s1;
  }
}

// ---------------------------------------------------------------------------
extern "C" void kernel_launch(void* const* d_in, const int* in_sizes, int n_in,
                              void* d_out, int out_size, void* d_ws, size_t ws_size,
                              hipStream_t stream)
{
  const float* x      = (const float*)d_in[0];
  const float* qkv_w  = (const float*)d_in[1];
  const float* qkv_b  = (const float*)d_in[2];
  const float* proj_w = (const float*)d_in[3];
  const float* proj_b = (const float*)d_in[4];
  float* out = (float*)d_out;

  // ws (bf16 elems): [xb|AO] | Qt | Kt | Vt | qkv_wb | proj_wb  = 55.05 MB
  unsigned short* ws = (unsigned short*)d_ws;
  unsigned short* xb  = ws;                  // x as bf16; dead after QKV gemm
  unsigned short* Qt  = ws + 6291456;
  unsigned short* Kt  = Qt + 6291456;
  unsigned short* Vt  = Kt + 6291456;
  unsigned short* qwb = Vt + 6291456;        // 2304x768 bf16
  unsigned short* pwb = qwb + 1769472;       // 768x768 bf16
  unsigned short* AO  = xb;                  // reuse (disjoint lifetime)

  cvt3<<<8448, 256, 0, stream>>>(x, xb, 1572864, qkv_w, qwb, 442368, proj_w, pwb);
  gemm_bt<0><<<dim3(64, 18), 256, 0, stream>>>(xb, qwb, qkv_b, Qt, Kt, Vt, nullptr);
  attn_fwd<<<768, 256, 0, stream>>>(Qt, Kt, Vt, AO);
  gemm_bt<1><<<dim3(64, 6), 256, 0, stream>>>(AO, pwb, proj_b, nullptr, nullptr, nullptr, out);
}

// Round 12
// 103.565 us; speedup vs baseline: 1.1226x; 1.1226x over previous
//
#include <hip/hip_runtime.h>
#include <hip/hip_bf16.h>

// Attention block: y = proj(softmax(QK^T/sqrt(d)) V), QKV from one GEMM.
// B=8, S=1024, DIM=768, H=12, HD=64.  bf16 MFMA w/ fp32 accum throughout.

typedef __attribute__((ext_vector_type(4)))  float f32x4;
typedef __attribute__((ext_vector_type(16))) float f32x16;
typedef __attribute__((ext_vector_type(8)))  short short8;
typedef __attribute__((ext_vector_type(4)))  short short4v;
typedef __attribute__((ext_vector_type(2)))  unsigned int uint2v;
typedef __attribute__((ext_vector_type(4)))  unsigned int uint4v;

__device__ __forceinline__ unsigned short f2bf_hw(float f) {
  return __builtin_bit_cast(unsigned short, __float2bfloat16(f));       // hw cvt, RNE
}
__device__ __forceinline__ unsigned int pk2bf(float a, float b) {
  return (unsigned int)f2bf_hw(a) | ((unsigned int)f2bf_hw(b) << 16);   // compiler packs
}

#define MFMA16(a, b, c) __builtin_amdgcn_mfma_f32_16x16x32_bf16((a), (b), (c), 0, 0, 0)
#define MFMA32(a, b, c) __builtin_amdgcn_mfma_f32_32x32x16_bf16((a), (b), (c), 0, 0, 0)

// Q pre-scale: 1/sqrt(64) * log2(e)  -> QK^T scores land in exp2 domain
#define QSCALE 0.18033688011112042f

__device__ __forceinline__ void gload_lds16(const unsigned short* g, char* lds) {
  __builtin_amdgcn_global_load_lds(
      (const __attribute__((address_space(1))) unsigned int*)g,
      (__attribute__((address_space(3))) unsigned int*)lds, 16, 0, 0);
}

// ---------------------------------------------------------------------------
// fp32 -> bf16 for x, qkv_w, proj_w in one launch (sizes in f32x4 units).
// ---------------------------------------------------------------------------
__global__ __launch_bounds__(256)
void cvt3(const float* __restrict__ a, unsigned short* __restrict__ da, int na,
          const float* __restrict__ b, unsigned short* __restrict__ db, int nb,
          const float* __restrict__ c, unsigned short* __restrict__ dc)
{
  int i = blockIdx.x * 256 + threadIdx.x;
  const float* s; unsigned short* d;
  if (i < na)           { s = a; d = da; }
  else if (i < na + nb) { s = b; d = db; i -= na; }
  else                  { s = c; d = dc; i -= na + nb; }
  f32x4 v = ((const f32x4*)s)[i];
  short4v h;
  h[0] = (short)f2bf_hw(v[0]); h[1] = (short)f2bf_hw(v[1]);
  h[2] = (short)f2bf_hw(v[2]); h[3] = (short)f2bf_hw(v[3]);
  ((short4v*)d)[i] = h;
}

// ---------------------------------------------------------------------------
// BT-GEMM (unchanged from R6): both operands bf16 via global_load_lds,
// double-buffered, counted vmcnt(8). 128x128x64, 4 waves.
// ---------------------------------------------------------------------------
template<int EPI>
__global__ __launch_bounds__(256)
void gemm_bt(const unsigned short* __restrict__ A, const unsigned short* __restrict__ Wb,
             const float* __restrict__ bias,
             unsigned short* __restrict__ Qt, unsigned short* __restrict__ Kt,
             unsigned short* __restrict__ Vt, float* __restrict__ Out)
{
  __shared__ char lds[65536];              // [buf][A 16K | W 16K]
  const int tid = threadIdx.x;
  const int w = tid >> 6, l = tid & 63, lr = l & 15, lg = l >> 4;
  const int wr = w >> 1, wc = w & 1;
  const int m0 = blockIdx.x * 128, n0 = blockIdx.y * 128;
  f32x4 acc[4][4] = {};

  const int srow = tid >> 3;
  const int cb   = ((tid & 7) << 4) ^ ((srow & 7) << 4);
  const unsigned short* pA = A  + (size_t)(m0 + srow) * 768 + (cb >> 1);
  const unsigned short* pW = Wb + (size_t)(n0 + srow) * 768 + (cb >> 1);
  char* const ldsA = lds + tid * 16;
  char* const ldsW = lds + 16384 + tid * 16;

  #pragma unroll
  for (int c = 0; c < 4; ++c) gload_lds16(pA + c * 32 * 768, ldsA + c * 4096);
  #pragma unroll
  for (int c = 0; c < 4; ++c) gload_lds16(pW + c * 32 * 768, ldsW + c * 4096);
  pA += 64; pW += 64;

  for (int kt = 0; kt < 12; ++kt) {
    if (kt < 11) {
      const int nb = ((kt + 1) & 1) * 32768;
      #pragma unroll
      for (int c = 0; c < 4; ++c) gload_lds16(pA + c * 32 * 768, ldsA + nb + c * 4096);
      #pragma unroll
      for (int c = 0; c < 4; ++c) gload_lds16(pW + c * 32 * 768, ldsW + nb + c * 4096);
      pA += 64; pW += 64;
      asm volatile("s_waitcnt vmcnt(8)" ::: "memory");
    } else {
      asm volatile("s_waitcnt vmcnt(0)" ::: "memory");
    }
    __builtin_amdgcn_s_barrier();
    __builtin_amdgcn_sched_barrier(0);

    const char* Ab = lds + (kt & 1) * 32768;
    const char* Bb = Ab + 16384;
    #pragma unroll
    for (int kc = 0; kc < 2; ++kc) {
      short8 af[4], bfr[4];
      #pragma unroll
      for (int mf = 0; mf < 4; ++mf) {
        const int row = wr * 64 + mf * 16 + lr;
        af[mf] = *(const short8*)(Ab + row * 128 +
                                  ((kc * 64 + lg * 16) ^ ((row & 7) << 4)));
      }
      #pragma unroll
      for (int nf = 0; nf < 4; ++nf) {
        const int row = wc * 64 + nf * 16 + lr;
        bfr[nf] = *(const short8*)(Bb + row * 128 +
                                   ((kc * 64 + lg * 16) ^ ((row & 7) << 4)));
      }
      #pragma unroll
      for (int mf = 0; mf < 4; ++mf)
        #pragma unroll
        for (int nf = 0; nf < 4; ++nf)
          acc[mf][nf] = MFMA16(af[mf], bfr[nf], acc[mf][nf]);
    }
    __builtin_amdgcn_s_barrier();
  }

  if constexpr (EPI == 0) {
    const int tt = blockIdx.y / 6;         // 0=Q 1=K 2=V
    const int h = (blockIdx.y % 6) * 2 + wc;
    #pragma unroll
    for (int nf = 0; nf < 4; ++nf) {
      const int dh = nf * 16 + lr;
      const float bv = bias[n0 + wc * 64 + dh];
      #pragma unroll
      for (int mf = 0; mf < 4; ++mf) {
        const int mb = m0 + wr * 64 + mf * 16 + lg * 4;
        const int b_ = mb >> 10, s_ = mb & 1023;
        f32x4 c = acc[mf][nf];
        if (tt == 0) {
          unsigned short* p = Qt + ((b_ * 12 + h) * 1024 + s_) * 64 + dh;
          #pragma unroll
          for (int j = 0; j < 4; ++j) p[j * 64] = f2bf_hw((c[j] + bv) * QSCALE);
        } else if (tt == 1) {
          unsigned short* p = Kt + ((b_ * 12 + h) * 1024 + s_) * 64 + dh;
          #pragma unroll
          for (int j = 0; j < 4; ++j) p[j * 64] = f2bf_hw(c[j] + bv);
        } else {
          short4v pk;
          #pragma unroll
          for (int j = 0; j < 4; ++j) pk[j] = (short)f2bf_hw(c[j] + bv);
          *(short4v*)(Vt + ((b_ * 12 + h) * 64 + dh) * 1024 + s_) = pk;  // V^T (d,s)
        }
      }
    }
  } else {
    #pragma unroll
    for (int nf = 0; nf < 4; ++nf) {
      const int e = n0 + wc * 64 + nf * 16 + lr;
      const float bv = bias[e];
      #pragma unroll
      for (int mf = 0; mf < 4; ++mf) {
        const int mb = m0 + wr * 64 + mf * 16 + lg * 4;
        #pragma unroll
        for (int j = 0; j < 4; ++j)
          Out[(size_t)(mb + j) * 768 + e] = acc[mf][nf][j] + bv;
      }
    }
  }
}

// ---------------------------------------------------------------------------
// Flash attention fwd v7 — v6 + softmax VALU/DS diet:
//  * P-frag build: 4 x permlane32_swap (VALU) replaces 8 ds_bpermute shuffles
//    + 8 selects.  r0=[a.lo|b.lo], r1=[a.hi|b.hi] per swap.
//  * lsum cross-lane reduce hoisted out of the loop (plain sum, no rescale).
//  * exp2 via __builtin_amdgcn_exp2f = single v_exp_f32 (no ocml fixup).
// Grid 768 = 96 heads x 8 q-tiles(128).  4 waves x 32 q-rows, in-reg P,
// no max tracking (scores bounded; softmax shift-invariant).  LDS 32 KB.
// C layout (m74/m101): col=lane&31, row=(reg&3)+8*(reg>>2)+4*(lane>>5).
// ---------------------------------------------------------------------------
__global__ __launch_bounds__(256, 4)
void attn_fwd(const unsigned short* __restrict__ Qt,
              const unsigned short* __restrict__ Kt,
              const unsigned short* __restrict__ Vt,
              unsigned short* __restrict__ AO)
{
  __shared__ char lds[32768];
  char* Ks = lds;                 // 2 x 8192: [64 key rows][128 B] swz
  char* Vs = lds + 16384;         // 2 x 8192: [64 d rows][128 B] swz

  const int bid = blockIdx.x;
  const int bh = bid % 96, qt = bid / 96;       // same head -> same XCD (96%8==0)
  const int tid = threadIdx.x, w = tid >> 6, l = tid & 63;
  const int l31 = l & 31, hi = l >> 5;
  const unsigned short* Qh = Qt + bh * 65536;
  const unsigned short* Kh = Kt + bh * 65536;
  const unsigned short* Vh = Vt + bh * 65536;   // (d, s) layout
  const int b_ = bh / 12, h = bh % 12;

  const int srow = tid >> 3;                    // staging rows 0..31 (+32)
  const int cb   = ((tid & 7) << 4) ^ ((srow & 7) << 4);
  char* const ldsK = Ks + tid * 16;
  char* const ldsV = Vs + tid * 16;

  // Q B-frags (col=q=lane&31, k=d=hi*8+e), held in regs all kernel
  const int q0 = qt * 128 + w * 32;
  const unsigned short* qp = Qh + (size_t)(q0 + l31) * 64 + hi * 8;
  short8 bq[4];
  #pragma unroll
  for (int kk = 0; kk < 4; ++kk) bq[kk] = *(const short8*)(qp + kk * 16);

  // prologue: stage KV tile 0 into buf 0 (landing guarded by loop-top wait)
  #pragma unroll
  for (int c = 0; c < 2; ++c)
    gload_lds16(Kh + (size_t)(srow + c * 32) * 64 + (cb >> 1), ldsK + c * 4096);
  #pragma unroll
  for (int c = 0; c < 2; ++c)
    gload_lds16(Vh + (size_t)(srow + c * 32) * 1024 + (cb >> 1), ldsV + c * 4096);

  float lsum = 0.f;                // per-lane PARTIAL (16 of 32 keys/step)
  f32x16 o0 = {}, o1 = {};         // O^T: col q, rows d (dblk 0: 0-31, 1: 32-63)

  for (int t = 0; t < 16; ++t) {
    const int cur = t & 1;
    // ---- stage next KV tile (async; stays in flight across the barrier) ----
    if (t < 15) {
      const int nk = (t + 1) * 64;
      const int nb = (cur ^ 1) * 8192;
      #pragma unroll
      for (int c = 0; c < 2; ++c)
        gload_lds16(Kh + (size_t)(nk + srow + c * 32) * 64 + (cb >> 1),
                    ldsK + nb + c * 4096);
      #pragma unroll
      for (int c = 0; c < 2; ++c)
        gload_lds16(Vh + (size_t)(srow + c * 32) * 1024 + nk + (cb >> 1),
                    ldsV + nb + c * 4096);
      asm volatile("s_waitcnt vmcnt(4)" ::: "memory");  // own tile-t loads landed
    } else {
      asm volatile("s_waitcnt vmcnt(0)" ::: "memory");
    }
    __builtin_amdgcn_s_barrier();                       // all waves' tile-t landed
    __builtin_amdgcn_sched_barrier(0);

    const char* Kb = Ks + cur * 8192;
    const char* Vb = Vs + cur * 8192;

    #pragma unroll
    for (int kb = 0; kb < 2; ++kb) {
      // ---- S^T = K Q^T (A = K[32 keys][16 d], B = Q^T) ----
      const int krow = kb * 32 + l31;
      const char* kbase = Kb + krow * 128;
      const int kswz = (krow & 7) << 4;
      f32x16 s = {};
      __builtin_amdgcn_s_setprio(1);
      #pragma unroll
      for (int kk = 0; kk < 4; ++kk) {
        short8 ka = *(const short8*)(kbase + ((kk * 32 + hi * 16) ^ kswz));
        s = MFMA32(ka, bq[kk], s);
      }
      __builtin_amdgcn_s_setprio(0);

      // ---- softmax numerator: P = exp2(s), raw v_exp_f32 ----
      unsigned int pk_[8];
      float t0 = 0.f, t1 = 0.f;
      #pragma unroll
      for (int i = 0; i < 8; ++i) {
        const float pa = __builtin_amdgcn_exp2f(s[2 * i]);
        const float pb = __builtin_amdgcn_exp2f(s[2 * i + 1]);
        if (i & 1) t1 += pa + pb; else t0 += pa + pb;
        pk_[i] = pk2bf(pa, pb);
      }
      lsum += t0 + t1;   // per-lane partial; cross-lane reduce at epilogue

      // ---- build PV B-frags: 4 permlane32_swap (r0=[a.lo|b.lo], r1=[a.hi|b.hi]) ----
      const uint2v r02 = __builtin_amdgcn_permlane32_swap(pk_[0], pk_[2], false, false);
      const uint2v r13 = __builtin_amdgcn_permlane32_swap(pk_[1], pk_[3], false, false);
      const uint2v r46 = __builtin_amdgcn_permlane32_swap(pk_[4], pk_[6], false, false);
      const uint2v r57 = __builtin_amdgcn_permlane32_swap(pk_[5], pk_[7], false, false);
      uint4v b0v, b1v;
      b0v[0] = r02[0]; b0v[1] = r13[0]; b0v[2] = r02[1]; b0v[3] = r13[1];
      b1v[0] = r46[0]; b1v[1] = r57[0]; b1v[2] = r46[1]; b1v[3] = r57[1];
      const short8 pb0 = __builtin_bit_cast(short8, b0v);
      const short8 pb1 = __builtin_bit_cast(short8, b1v);

      // ---- O^T += V^T P^T (A = V^T[d][16 keys], B = P[16 keys][q]) ----
      const int vswz = (l31 & 7) << 4;      // (row&7) same for both dblks
      __builtin_amdgcn_s_setprio(1);
      #pragma unroll
      for (int kk = 0; kk < 2; ++kk) {
        const short8 pbk = kk ? pb1 : pb0;
        const int koff = kb * 64 + kk * 32 + hi * 16;
        short8 va0 = *(const short8*)(Vb + l31 * 128 + (koff ^ vswz));
        o0 = MFMA32(va0, pbk, o0);
        short8 va1 = *(const short8*)(Vb + (32 + l31) * 128 + (koff ^ vswz));
        o1 = MFMA32(va1, pbk, o1);
      }
      __builtin_amdgcn_s_setprio(0);
    }

    __builtin_amdgcn_s_barrier();   // reads of buf cur done before overwrite
  }

  // ---- epilogue: single cross-lane lsum reduce, lane-local normalize ----
  lsum += __shfl_xor(lsum, 32);
  const float inv = 1.f / lsum;
  unsigned short* aop = AO + ((size_t)(b_ * 1024 + q0 + l31)) * 768 + h * 64;
  #pragma unroll
  for (int g = 0; g < 4; ++g) {
    uint2v s0, s1;
    s0[0] = pk2bf(o0[4 * g] * inv,     o0[4 * g + 1] * inv);
    s0[1] = pk2bf(o0[4 * g + 2] * inv, o0[4 * g + 3] * inv);
    *(uint2v*)(aop + g * 8 + 4 * hi) = s0;
    s1[0] = pk2bf(o1[4 * g] * inv,     o1[4 * g + 1] * inv);
    s1[1] = pk2bf(o1[4 * g + 2] * inv, o1[4 * g + 3] * inv);
    *(uint2v*)(aop + 32 + g * 8 + 4 * hi) = s1;
  }
}

// ---------------------------------------------------------------------------
extern "C" void kernel_launch(void* const* d_in, const int* in_sizes, int n_in,
                              void* d_out, int out_size, void* d_ws, size_t ws_size,
                              hipStream_t stream)
{
  const float* x      = (const float*)d_in[0];
  const float* qkv_w  = (const float*)d_in[1];
  const float* qkv_b  = (const float*)d_in[2];
  const float* proj_w = (const float*)d_in[3];
  const float* proj_b = (const float*)d_in[4];
  float* out = (float*)d_out;

  // ws (bf16 elems): [xb|AO] | Qt | Kt | Vt | qkv_wb | proj_wb  = 55.05 MB
  unsigned short* ws = (unsigned short*)d_ws;
  unsigned short* xb  = ws;                  // x as bf16; dead after QKV gemm
  unsigned short* Qt  = ws + 6291456;
  unsigned short* Kt  = Qt + 6291456;
  unsigned short* Vt  = Kt + 6291456;
  unsigned short* qwb = Vt + 6291456;        // 2304x768 bf16
  unsigned short* pwb = qwb + 1769472;       // 768x768 bf16
  unsigned short* AO  = xb;                  // reuse (disjoint lifetime)

  cvt3<<<8448, 256, 0, stream>>>(x, xb, 1572864, qkv_w, qwb, 442368, proj_w, pwb);
  gemm_bt<0><<<dim3(64, 18), 256, 0, stream>>>(xb, qwb, qkv_b, Qt, Kt, Vt, nullptr);
  attn_fwd<<<768, 256, 0, stream>>>(Qt, Kt, Vt, AO);
  gemm_bt<1><<<dim3(64, 6), 256, 0, stream>>>(AO, pwb, proj_b, nullptr, nullptr, nullptr, out);
}

// Round 13
// 103.062 us; speedup vs baseline: 1.1281x; 1.0049x over previous
//
#include <hip/hip_runtime.h>
#include <hip/hip_bf16.h>

// Attention block: y = proj(softmax(QK^T/sqrt(d)) V), QKV from one GEMM.
// B=8, S=1024, DIM=768, H=12, HD=64.  bf16 MFMA w/ fp32 accum throughout.

typedef __attribute__((ext_vector_type(4)))  float f32x4;
typedef __attribute__((ext_vector_type(16))) float f32x16;
typedef __attribute__((ext_vector_type(8)))  short short8;
typedef __attribute__((ext_vector_type(4)))  short short4v;
typedef __attribute__((ext_vector_type(2)))  unsigned int uint2v;
typedef __attribute__((ext_vector_type(4)))  unsigned int uint4v;

__device__ __forceinline__ unsigned short f2bf_hw(float f) {
  return __builtin_bit_cast(unsigned short, __float2bfloat16(f));       // hw cvt, RNE
}
__device__ __forceinline__ unsigned int pk2bf(float a, float b) {
  return (unsigned int)f2bf_hw(a) | ((unsigned int)f2bf_hw(b) << 16);   // compiler packs
}

#define MFMA16(a, b, c) __builtin_amdgcn_mfma_f32_16x16x32_bf16((a), (b), (c), 0, 0, 0)
#define MFMA32(a, b, c) __builtin_amdgcn_mfma_f32_32x32x16_bf16((a), (b), (c), 0, 0, 0)

// Q pre-scale: 1/sqrt(64) * log2(e)  -> QK^T scores land in exp2 domain
#define QSCALE 0.18033688011112042f

__device__ __forceinline__ void gload_lds16(const unsigned short* g, char* lds) {
  __builtin_amdgcn_global_load_lds(
      (const __attribute__((address_space(1))) unsigned int*)g,
      (__attribute__((address_space(3))) unsigned int*)lds, 16, 0, 0);
}

// ---------------------------------------------------------------------------
// fp32 -> bf16 for x, qkv_w, proj_w in one launch (sizes in f32x4 units).
// ---------------------------------------------------------------------------
__global__ __launch_bounds__(256)
void cvt3(const float* __restrict__ a, unsigned short* __restrict__ da, int na,
          const float* __restrict__ b, unsigned short* __restrict__ db, int nb,
          const float* __restrict__ c, unsigned short* __restrict__ dc)
{
  int i = blockIdx.x * 256 + threadIdx.x;
  const float* s; unsigned short* d;
  if (i < na)           { s = a; d = da; }
  else if (i < na + nb) { s = b; d = db; i -= na; }
  else                  { s = c; d = dc; i -= na + nb; }
  f32x4 v = ((const f32x4*)s)[i];
  short4v h;
  h[0] = (short)f2bf_hw(v[0]); h[1] = (short)f2bf_hw(v[1]);
  h[2] = (short)f2bf_hw(v[2]); h[3] = (short)f2bf_hw(v[3]);
  ((short4v*)d)[i] = h;
}

// ---------------------------------------------------------------------------
// BT-GEMM (unchanged from R6): both operands bf16 via global_load_lds,
// double-buffered, counted vmcnt(8). 128x128x64, 4 waves.
// ---------------------------------------------------------------------------
template<int EPI>
__global__ __launch_bounds__(256)
void gemm_bt(const unsigned short* __restrict__ A, const unsigned short* __restrict__ Wb,
             const float* __restrict__ bias,
             unsigned short* __restrict__ Qt, unsigned short* __restrict__ Kt,
             unsigned short* __restrict__ Vt, float* __restrict__ Out)
{
  __shared__ char lds[65536];              // [buf][A 16K | W 16K]
  const int tid = threadIdx.x;
  const int w = tid >> 6, l = tid & 63, lr = l & 15, lg = l >> 4;
  const int wr = w >> 1, wc = w & 1;
  const int m0 = blockIdx.x * 128, n0 = blockIdx.y * 128;
  f32x4 acc[4][4] = {};

  const int srow = tid >> 3;
  const int cb   = ((tid & 7) << 4) ^ ((srow & 7) << 4);
  const unsigned short* pA = A  + (size_t)(m0 + srow) * 768 + (cb >> 1);
  const unsigned short* pW = Wb + (size_t)(n0 + srow) * 768 + (cb >> 1);
  char* const ldsA = lds + tid * 16;
  char* const ldsW = lds + 16384 + tid * 16;

  #pragma unroll
  for (int c = 0; c < 4; ++c) gload_lds16(pA + c * 32 * 768, ldsA + c * 4096);
  #pragma unroll
  for (int c = 0; c < 4; ++c) gload_lds16(pW + c * 32 * 768, ldsW + c * 4096);
  pA += 64; pW += 64;

  for (int kt = 0; kt < 12; ++kt) {
    if (kt < 11) {
      const int nb = ((kt + 1) & 1) * 32768;
      #pragma unroll
      for (int c = 0; c < 4; ++c) gload_lds16(pA + c * 32 * 768, ldsA + nb + c * 4096);
      #pragma unroll
      for (int c = 0; c < 4; ++c) gload_lds16(pW + c * 32 * 768, ldsW + nb + c * 4096);
      pA += 64; pW += 64;
      asm volatile("s_waitcnt vmcnt(8)" ::: "memory");
    } else {
      asm volatile("s_waitcnt vmcnt(0)" ::: "memory");
    }
    __builtin_amdgcn_s_barrier();
    __builtin_amdgcn_sched_barrier(0);

    const char* Ab = lds + (kt & 1) * 32768;
    const char* Bb = Ab + 16384;
    #pragma unroll
    for (int kc = 0; kc < 2; ++kc) {
      short8 af[4], bfr[4];
      #pragma unroll
      for (int mf = 0; mf < 4; ++mf) {
        const int row = wr * 64 + mf * 16 + lr;
        af[mf] = *(const short8*)(Ab + row * 128 +
                                  ((kc * 64 + lg * 16) ^ ((row & 7) << 4)));
      }
      #pragma unroll
      for (int nf = 0; nf < 4; ++nf) {
        const int row = wc * 64 + nf * 16 + lr;
        bfr[nf] = *(const short8*)(Bb + row * 128 +
                                   ((kc * 64 + lg * 16) ^ ((row & 7) << 4)));
      }
      #pragma unroll
      for (int mf = 0; mf < 4; ++mf)
        #pragma unroll
        for (int nf = 0; nf < 4; ++nf)
          acc[mf][nf] = MFMA16(af[mf], bfr[nf], acc[mf][nf]);
    }
    __builtin_amdgcn_s_barrier();
  }

  if constexpr (EPI == 0) {
    const int tt = blockIdx.y / 6;         // 0=Q 1=K 2=V
    const int h = (blockIdx.y % 6) * 2 + wc;
    #pragma unroll
    for (int nf = 0; nf < 4; ++nf) {
      const int dh = nf * 16 + lr;
      const float bv = bias[n0 + wc * 64 + dh];
      #pragma unroll
      for (int mf = 0; mf < 4; ++mf) {
        const int mb = m0 + wr * 64 + mf * 16 + lg * 4;
        const int b_ = mb >> 10, s_ = mb & 1023;
        f32x4 c = acc[mf][nf];
        if (tt == 0) {
          unsigned short* p = Qt + ((b_ * 12 + h) * 1024 + s_) * 64 + dh;
          #pragma unroll
          for (int j = 0; j < 4; ++j) p[j * 64] = f2bf_hw((c[j] + bv) * QSCALE);
        } else if (tt == 1) {
          unsigned short* p = Kt + ((b_ * 12 + h) * 1024 + s_) * 64 + dh;
          #pragma unroll
          for (int j = 0; j < 4; ++j) p[j * 64] = f2bf_hw(c[j] + bv);
        } else {
          short4v pk;
          #pragma unroll
          for (int j = 0; j < 4; ++j) pk[j] = (short)f2bf_hw(c[j] + bv);
          *(short4v*)(Vt + ((b_ * 12 + h) * 64 + dh) * 1024 + s_) = pk;  // V^T (d,s)
        }
      }
    }
  } else {
    #pragma unroll
    for (int nf = 0; nf < 4; ++nf) {
      const int e = n0 + wc * 64 + nf * 16 + lr;
      const float bv = bias[e];
      #pragma unroll
      for (int mf = 0; mf < 4; ++mf) {
        const int mb = m0 + wr * 64 + mf * 16 + lg * 4;
        #pragma unroll
        for (int j = 0; j < 4; ++j)
          Out[(size_t)(mb + j) * 768 + e] = acc[mf][nf][j] + bv;
      }
    }
  }
}

// ---------------------------------------------------------------------------
// Flash attention fwd v8 — v7 + intra-wave MFMA/VALU pipelining:
// issue BOTH QK^T batches (s0: keys 0-31, s1: keys 32-63) before softmax.
// softmax(s0) runs on the VALU while s1's MFMA chain executes in the matrix
// pipe (MFMA only blocks on consume).  Order: QK0,QK1 | SM0,PV0 | SM1,PV1.
// Grid 768 = 96 heads x 8 q-tiles(128).  4 waves x 32 q-rows, in-reg P,
// no max tracking (scores bounded; softmax shift-invariant).  LDS 32 KB.
// C layout (m74/m101): col=lane&31, row=(reg&3)+8*(reg>>2)+4*(lane>>5).
// ---------------------------------------------------------------------------
__global__ __launch_bounds__(256, 4)
void attn_fwd(const unsigned short* __restrict__ Qt,
              const unsigned short* __restrict__ Kt,
              const unsigned short* __restrict__ Vt,
              unsigned short* __restrict__ AO)
{
  __shared__ char lds[32768];
  char* Ks = lds;                 // 2 x 8192: [64 key rows][128 B] swz
  char* Vs = lds + 16384;         // 2 x 8192: [64 d rows][128 B] swz

  const int bid = blockIdx.x;
  const int bh = bid % 96, qt = bid / 96;       // same head -> same XCD (96%8==0)
  const int tid = threadIdx.x, w = tid >> 6, l = tid & 63;
  const int l31 = l & 31, hi = l >> 5;
  const unsigned short* Qh = Qt + bh * 65536;
  const unsigned short* Kh = Kt + bh * 65536;
  const unsigned short* Vh = Vt + bh * 65536;   // (d, s) layout
  const int b_ = bh / 12, h = bh % 12;

  const int srow = tid >> 3;                    // staging rows 0..31 (+32)
  const int cb   = ((tid & 7) << 4) ^ ((srow & 7) << 4);
  char* const ldsK = Ks + tid * 16;
  char* const ldsV = Vs + tid * 16;

  // Q B-frags (col=q=lane&31, k=d=hi*8+e), held in regs all kernel
  const int q0 = qt * 128 + w * 32;
  const unsigned short* qp = Qh + (size_t)(q0 + l31) * 64 + hi * 8;
  short8 bq[4];
  #pragma unroll
  for (int kk = 0; kk < 4; ++kk) bq[kk] = *(const short8*)(qp + kk * 16);

  // prologue: stage KV tile 0 into buf 0 (landing guarded by loop-top wait)
  #pragma unroll
  for (int c = 0; c < 2; ++c)
    gload_lds16(Kh + (size_t)(srow + c * 32) * 64 + (cb >> 1), ldsK + c * 4096);
  #pragma unroll
  for (int c = 0; c < 2; ++c)
    gload_lds16(Vh + (size_t)(srow + c * 32) * 1024 + (cb >> 1), ldsV + c * 4096);

  float lsum = 0.f;                // per-lane PARTIAL (16 of 32 keys/step)
  f32x16 o0 = {}, o1 = {};         // O^T: col q, rows d (dblk 0: 0-31, 1: 32-63)

  const int kswz = (l31 & 7) << 4;   // row&7 identical for rows l31 and l31+32
  const int vswz = kswz;

  for (int t = 0; t < 16; ++t) {
    const int cur = t & 1;
    // ---- stage next KV tile (async; stays in flight across the barrier) ----
    if (t < 15) {
      const int nk = (t + 1) * 64;
      const int nb = (cur ^ 1) * 8192;
      #pragma unroll
      for (int c = 0; c < 2; ++c)
        gload_lds16(Kh + (size_t)(nk + srow + c * 32) * 64 + (cb >> 1),
                    ldsK + nb + c * 4096);
      #pragma unroll
      for (int c = 0; c < 2; ++c)
        gload_lds16(Vh + (size_t)(srow + c * 32) * 1024 + nk + (cb >> 1),
                    ldsV + nb + c * 4096);
      asm volatile("s_waitcnt vmcnt(4)" ::: "memory");  // own tile-t loads landed
    } else {
      asm volatile("s_waitcnt vmcnt(0)" ::: "memory");
    }
    __builtin_amdgcn_s_barrier();                       // all waves' tile-t landed
    __builtin_amdgcn_sched_barrier(0);

    const char* Kb = Ks + cur * 8192;
    const char* Vb = Vs + cur * 8192;
    const char* kbase0 = Kb + l31 * 128;          // keys 0-31
    const char* kbase1 = Kb + (32 + l31) * 128;   // keys 32-63

    // ---- QK^T both halves up front: s1's chain overlaps softmax(s0) ----
    f32x16 s0v = {}, s1v = {};
    __builtin_amdgcn_s_setprio(1);
    #pragma unroll
    for (int kk = 0; kk < 4; ++kk) {
      short8 ka = *(const short8*)(kbase0 + ((kk * 32 + hi * 16) ^ kswz));
      s0v = MFMA32(ka, bq[kk], s0v);
    }
    #pragma unroll
    for (int kk = 0; kk < 4; ++kk) {
      short8 ka = *(const short8*)(kbase1 + ((kk * 32 + hi * 16) ^ kswz));
      s1v = MFMA32(ka, bq[kk], s1v);
    }
    __builtin_amdgcn_s_setprio(0);

    #pragma unroll
    for (int kb = 0; kb < 2; ++kb) {
      const f32x16 s = kb ? s1v : s0v;

      // ---- softmax numerator: P = exp2(s), raw v_exp_f32 ----
      unsigned int pk_[8];
      float t0 = 0.f, t1 = 0.f;
      #pragma unroll
      for (int i = 0; i < 8; ++i) {
        const float pa = __builtin_amdgcn_exp2f(s[2 * i]);
        const float pb = __builtin_amdgcn_exp2f(s[2 * i + 1]);
        if (i & 1) t1 += pa + pb; else t0 += pa + pb;
        pk_[i] = pk2bf(pa, pb);
      }
      lsum += t0 + t1;   // per-lane partial; cross-lane reduce at epilogue

      // ---- build PV B-frags: 4 permlane32_swap ----
      const uint2v r02 = __builtin_amdgcn_permlane32_swap(pk_[0], pk_[2], false, false);
      const uint2v r13 = __builtin_amdgcn_permlane32_swap(pk_[1], pk_[3], false, false);
      const uint2v r46 = __builtin_amdgcn_permlane32_swap(pk_[4], pk_[6], false, false);
      const uint2v r57 = __builtin_amdgcn_permlane32_swap(pk_[5], pk_[7], false, false);
      uint4v b0v, b1v;
      b0v[0] = r02[0]; b0v[1] = r13[0]; b0v[2] = r02[1]; b0v[3] = r13[1];
      b1v[0] = r46[0]; b1v[1] = r57[0]; b1v[2] = r46[1]; b1v[3] = r57[1];
      const short8 pb0 = __builtin_bit_cast(short8, b0v);
      const short8 pb1 = __builtin_bit_cast(short8, b1v);

      // ---- O^T += V^T P^T (A = V^T[d][16 keys], B = P[16 keys][q]) ----
      __builtin_amdgcn_s_setprio(1);
      #pragma unroll
      for (int kk = 0; kk < 2; ++kk) {
        const short8 pbk = kk ? pb1 : pb0;
        const int koff = kb * 64 + kk * 32 + hi * 16;
        short8 va0 = *(const short8*)(Vb + l31 * 128 + (koff ^ vswz));
        o0 = MFMA32(va0, pbk, o0);
        short8 va1 = *(const short8*)(Vb + (32 + l31) * 128 + (koff ^ vswz));
        o1 = MFMA32(va1, pbk, o1);
      }
      __builtin_amdgcn_s_setprio(0);
    }

    __builtin_amdgcn_s_barrier();   // reads of buf cur done before overwrite
  }

  // ---- epilogue: single cross-lane lsum reduce, lane-local normalize ----
  lsum += __shfl_xor(lsum, 32);
  const float inv = 1.f / lsum;
  unsigned short* aop = AO + ((size_t)(b_ * 1024 + q0 + l31)) * 768 + h * 64;
  #pragma unroll
  for (int g = 0; g < 4; ++g) {
    uint2v s0, s1;
    s0[0] = pk2bf(o0[4 * g] * inv,     o0[4 * g + 1] * inv);
    s0[1] = pk2bf(o0[4 * g + 2] * inv, o0[4 * g + 3] * inv);
    *(uint2v*)(aop + g * 8 + 4 * hi) = s0;
    s1[0] = pk2bf(o1[4 * g] * inv,     o1[4 * g + 1] * inv);
    s1[1] = pk2bf(o1[4 * g + 2] * inv, o1[4 * g + 3] * inv);
    *(uint2v*)(aop + 32 + g * 8 + 4 * hi) = s1;
  }
}

// ---------------------------------------------------------------------------
extern "C" void kernel_launch(void* const* d_in, const int* in_sizes, int n_in,
                              void* d_out, int out_size, void* d_ws, size_t ws_size,
                              hipStream_t stream)
{
  const float* x      = (const float*)d_in[0];
  const float* qkv_w  = (const float*)d_in[1];
  const float* qkv_b  = (const float*)d_in[2];
  const float* proj_w = (const float*)d_in[3];
  const float* proj_b = (const float*)d_in[4];
  float* out = (float*)d_out;

  // ws (bf16 elems): [xb|AO] | Qt | Kt | Vt | qkv_wb | proj_wb  = 55.05 MB
  unsigned short* ws = (unsigned short*)d_ws;
  unsigned short* xb  = ws;                  // x as bf16; dead after QKV gemm
  unsigned short* Qt  = ws + 6291456;
  unsigned short* Kt  = Qt + 6291456;
  unsigned short* Vt  = Kt + 6291456;
  unsigned short* qwb = Vt + 6291456;        // 2304x768 bf16
  unsigned short* pwb = qwb + 1769472;       // 768x768 bf16
  unsigned short* AO  = xb;                  // reuse (disjoint lifetime)

  cvt3<<<8448, 256, 0, stream>>>(x, xb, 1572864, qkv_w, qwb, 442368, proj_w, pwb);
  gemm_bt<0><<<dim3(64, 18), 256, 0, stream>>>(xb, qwb, qkv_b, Qt, Kt, Vt, nullptr);
  attn_fwd<<<768, 256, 0, stream>>>(Qt, Kt, Vt, AO);
  gemm_bt<1><<<dim3(64, 6), 256, 0, stream>>>(AO, pwb, proj_b, nullptr, nullptr, nullptr, out);
}

// Round 14
// 102.768 us; speedup vs baseline: 1.1313x; 1.0029x over previous
//
#include <hip/hip_runtime.h>
#include <hip/hip_bf16.h>

// Attention block: y = proj(softmax(QK^T/sqrt(d)) V), QKV from one GEMM.
// B=8, S=1024, DIM=768, H=12, HD=64.  bf16 MFMA w/ fp32 accum throughout.

typedef __attribute__((ext_vector_type(4)))  float f32x4;
typedef __attribute__((ext_vector_type(16))) float f32x16;
typedef __attribute__((ext_vector_type(8)))  short short8;
typedef __attribute__((ext_vector_type(4)))  short short4v;
typedef __attribute__((ext_vector_type(2)))  unsigned int uint2v;
typedef __attribute__((ext_vector_type(4)))  unsigned int uint4v;

__device__ __forceinline__ unsigned short f2bf_hw(float f) {
  return __builtin_bit_cast(unsigned short, __float2bfloat16(f));       // hw cvt, RNE
}
__device__ __forceinline__ unsigned int pk2bf(float a, float b) {
  return (unsigned int)f2bf_hw(a) | ((unsigned int)f2bf_hw(b) << 16);   // compiler packs
}

#define MFMA16(a, b, c) __builtin_amdgcn_mfma_f32_16x16x32_bf16((a), (b), (c), 0, 0, 0)
#define MFMA32(a, b, c) __builtin_amdgcn_mfma_f32_32x32x16_bf16((a), (b), (c), 0, 0, 0)

// Q pre-scale: 1/sqrt(64) * log2(e)  -> QK^T scores land in exp2 domain
#define QSCALE 0.18033688011112042f

__device__ __forceinline__ void gload_lds16(const unsigned short* g, char* lds) {
  __builtin_amdgcn_global_load_lds(
      (const __attribute__((address_space(1))) unsigned int*)g,
      (__attribute__((address_space(3))) unsigned int*)lds, 16, 0, 0);
}

// ---------------------------------------------------------------------------
// fp32 -> bf16 for x, qkv_w, proj_w in one launch (sizes in f32x4 units).
// ---------------------------------------------------------------------------
__global__ __launch_bounds__(256)
void cvt3(const float* __restrict__ a, unsigned short* __restrict__ da, int na,
          const float* __restrict__ b, unsigned short* __restrict__ db, int nb,
          const float* __restrict__ c, unsigned short* __restrict__ dc)
{
  int i = blockIdx.x * 256 + threadIdx.x;
  const float* s; unsigned short* d;
  if (i < na)           { s = a; d = da; }
  else if (i < na + nb) { s = b; d = db; i -= na; }
  else                  { s = c; d = dc; i -= na + nb; }
  f32x4 v = ((const f32x4*)s)[i];
  short4v h;
  h[0] = (short)f2bf_hw(v[0]); h[1] = (short)f2bf_hw(v[1]);
  h[2] = (short)f2bf_hw(v[2]); h[3] = (short)f2bf_hw(v[3]);
  ((short4v*)d)[i] = h;
}

// ---------------------------------------------------------------------------
// BT-GEMM (unchanged from R6): both operands bf16 via global_load_lds,
// double-buffered, counted vmcnt(8). 128x128x64, 4 waves.
// ---------------------------------------------------------------------------
template<int EPI>
__global__ __launch_bounds__(256)
void gemm_bt(const unsigned short* __restrict__ A, const unsigned short* __restrict__ Wb,
             const float* __restrict__ bias,
             unsigned short* __restrict__ Qt, unsigned short* __restrict__ Kt,
             unsigned short* __restrict__ Vt, float* __restrict__ Out)
{
  __shared__ char lds[65536];              // [buf][A 16K | W 16K]
  const int tid = threadIdx.x;
  const int w = tid >> 6, l = tid & 63, lr = l & 15, lg = l >> 4;
  const int wr = w >> 1, wc = w & 1;
  const int m0 = blockIdx.x * 128, n0 = blockIdx.y * 128;
  f32x4 acc[4][4] = {};

  const int srow = tid >> 3;
  const int cb   = ((tid & 7) << 4) ^ ((srow & 7) << 4);
  const unsigned short* pA = A  + (size_t)(m0 + srow) * 768 + (cb >> 1);
  const unsigned short* pW = Wb + (size_t)(n0 + srow) * 768 + (cb >> 1);
  char* const ldsA = lds + tid * 16;
  char* const ldsW = lds + 16384 + tid * 16;

  #pragma unroll
  for (int c = 0; c < 4; ++c) gload_lds16(pA + c * 32 * 768, ldsA + c * 4096);
  #pragma unroll
  for (int c = 0; c < 4; ++c) gload_lds16(pW + c * 32 * 768, ldsW + c * 4096);
  pA += 64; pW += 64;

  for (int kt = 0; kt < 12; ++kt) {
    if (kt < 11) {
      const int nb = ((kt + 1) & 1) * 32768;
      #pragma unroll
      for (int c = 0; c < 4; ++c) gload_lds16(pA + c * 32 * 768, ldsA + nb + c * 4096);
      #pragma unroll
      for (int c = 0; c < 4; ++c) gload_lds16(pW + c * 32 * 768, ldsW + nb + c * 4096);
      pA += 64; pW += 64;
      asm volatile("s_waitcnt vmcnt(8)" ::: "memory");
    } else {
      asm volatile("s_waitcnt vmcnt(0)" ::: "memory");
    }
    __builtin_amdgcn_s_barrier();
    __builtin_amdgcn_sched_barrier(0);

    const char* Ab = lds + (kt & 1) * 32768;
    const char* Bb = Ab + 16384;
    #pragma unroll
    for (int kc = 0; kc < 2; ++kc) {
      short8 af[4], bfr[4];
      #pragma unroll
      for (int mf = 0; mf < 4; ++mf) {
        const int row = wr * 64 + mf * 16 + lr;
        af[mf] = *(const short8*)(Ab + row * 128 +
                                  ((kc * 64 + lg * 16) ^ ((row & 7) << 4)));
      }
      #pragma unroll
      for (int nf = 0; nf < 4; ++nf) {
        const int row = wc * 64 + nf * 16 + lr;
        bfr[nf] = *(const short8*)(Bb + row * 128 +
                                   ((kc * 64 + lg * 16) ^ ((row & 7) << 4)));
      }
      #pragma unroll
      for (int mf = 0; mf < 4; ++mf)
        #pragma unroll
        for (int nf = 0; nf < 4; ++nf)
          acc[mf][nf] = MFMA16(af[mf], bfr[nf], acc[mf][nf]);
    }
    __builtin_amdgcn_s_barrier();
  }

  if constexpr (EPI == 0) {
    const int tt = blockIdx.y / 6;         // 0=Q 1=K 2=V
    const int h = (blockIdx.y % 6) * 2 + wc;
    #pragma unroll
    for (int nf = 0; nf < 4; ++nf) {
      const int dh = nf * 16 + lr;
      const float bv = bias[n0 + wc * 64 + dh];
      #pragma unroll
      for (int mf = 0; mf < 4; ++mf) {
        const int mb = m0 + wr * 64 + mf * 16 + lg * 4;
        const int b_ = mb >> 10, s_ = mb & 1023;
        f32x4 c = acc[mf][nf];
        if (tt == 0) {
          unsigned short* p = Qt + ((b_ * 12 + h) * 1024 + s_) * 64 + dh;
          #pragma unroll
          for (int j = 0; j < 4; ++j) p[j * 64] = f2bf_hw((c[j] + bv) * QSCALE);
        } else if (tt == 1) {
          unsigned short* p = Kt + ((b_ * 12 + h) * 1024 + s_) * 64 + dh;
          #pragma unroll
          for (int j = 0; j < 4; ++j) p[j * 64] = f2bf_hw(c[j] + bv);
        } else {
          short4v pk;
          #pragma unroll
          for (int j = 0; j < 4; ++j) pk[j] = (short)f2bf_hw(c[j] + bv);
          *(short4v*)(Vt + ((b_ * 12 + h) * 64 + dh) * 1024 + s_) = pk;  // V^T (d,s)
        }
      }
    }
  } else {
    #pragma unroll
    for (int nf = 0; nf < 4; ++nf) {
      const int e = n0 + wc * 64 + nf * 16 + lr;
      const float bv = bias[e];
      #pragma unroll
      for (int mf = 0; mf < 4; ++mf) {
        const int mb = m0 + wr * 64 + mf * 16 + lg * 4;
        #pragma unroll
        for (int j = 0; j < 4; ++j)
          Out[(size_t)(mb + j) * 768 + e] = acc[mf][nf][j] + bv;
      }
    }
  }
}

// ---------------------------------------------------------------------------
// Flash attention fwd v9 — v8 + 3-buffer rotation, ONE barrier per iter.
// stage(t+1)->buf[(t+1)%3]; compute reads buf[t%3]; staged buf was last read
// at compute(t-2), separated by barriers A(t-1),A(t) from any lagging wave
// (max skew 1 barrier; (t+1)%3 != (t-1)%3).  Each wave's own vmcnt(4) before
// A(t+1) guarantees its tile-(t+1) DMA landed before any reader passes it.
// Removes the end-of-iter re-convergence that lockstepped the 4 waves.
// Grid 768 = 96 heads x 8 q-tiles(128).  4 waves x 32 q-rows, in-reg P,
// no max tracking (scores bounded; softmax shift-invariant).  LDS 48 KB.
// C layout (m74/m101): col=lane&31, row=(reg&3)+8*(reg>>2)+4*(lane>>5).
// ---------------------------------------------------------------------------
__global__ __launch_bounds__(256, 3)
void attn_fwd(const unsigned short* __restrict__ Qt,
              const unsigned short* __restrict__ Kt,
              const unsigned short* __restrict__ Vt,
              unsigned short* __restrict__ AO)
{
  __shared__ char lds[49152];     // 3 bufs x 16384: [K 64x128B | V 64x128B] swz

  const int bid = blockIdx.x;
  const int bh = bid % 96, qt = bid / 96;       // same head -> same XCD (96%8==0)
  const int tid = threadIdx.x, w = tid >> 6, l = tid & 63;
  const int l31 = l & 31, hi = l >> 5;
  const unsigned short* Qh = Qt + bh * 65536;
  const unsigned short* Kh = Kt + bh * 65536;
  const unsigned short* Vh = Vt + bh * 65536;   // (d, s) layout
  const int b_ = bh / 12, h = bh % 12;

  const int srow = tid >> 3;                    // staging rows 0..31 (+32)
  const int cb   = ((tid & 7) << 4) ^ ((srow & 7) << 4);

  // Q B-frags (col=q=lane&31, k=d=hi*8+e), held in regs all kernel
  const int q0 = qt * 128 + w * 32;
  const unsigned short* qp = Qh + (size_t)(q0 + l31) * 64 + hi * 8;
  short8 bq[4];
  #pragma unroll
  for (int kk = 0; kk < 4; ++kk) bq[kk] = *(const short8*)(qp + kk * 16);

  // prologue: stage KV tile 0 into buf 0 (landing guarded by loop-top wait)
  #pragma unroll
  for (int c = 0; c < 2; ++c)
    gload_lds16(Kh + (size_t)(srow + c * 32) * 64 + (cb >> 1),
                lds + tid * 16 + c * 4096);
  #pragma unroll
  for (int c = 0; c < 2; ++c)
    gload_lds16(Vh + (size_t)(srow + c * 32) * 1024 + (cb >> 1),
                lds + 8192 + tid * 16 + c * 4096);

  float lsum = 0.f;                // per-lane PARTIAL (16 of 32 keys/step)
  f32x16 o0 = {}, o1 = {};         // O^T: col q, rows d (dblk 0: 0-31, 1: 32-63)

  const int kswz = (l31 & 7) << 4;   // row&7 identical for rows l31 and l31+32
  const int vswz = kswz;

  int bc = 0, bn = 1;              // buf indices: current, next (rotate mod 3)
  for (int t = 0; t < 16; ++t) {
    // ---- stage next KV tile into buf bn (async; in flight across barrier) ----
    if (t < 15) {
      const int nk = (t + 1) * 64;
      char* const stK = lds + bn * 16384 + tid * 16;
      char* const stV = stK + 8192;
      #pragma unroll
      for (int c = 0; c < 2; ++c)
        gload_lds16(Kh + (size_t)(nk + srow + c * 32) * 64 + (cb >> 1),
                    stK + c * 4096);
      #pragma unroll
      for (int c = 0; c < 2; ++c)
        gload_lds16(Vh + (size_t)(srow + c * 32) * 1024 + nk + (cb >> 1),
                    stV + c * 4096);
      asm volatile("s_waitcnt vmcnt(4)" ::: "memory");  // own tile-t loads landed
    } else {
      asm volatile("s_waitcnt vmcnt(0)" ::: "memory");
    }
    __builtin_amdgcn_s_barrier();                       // all waves' tile-t landed
    __builtin_amdgcn_sched_barrier(0);

    const char* Kb = lds + bc * 16384;
    const char* Vb = Kb + 8192;
    const char* kbase0 = Kb + l31 * 128;          // keys 0-31
    const char* kbase1 = Kb + (32 + l31) * 128;   // keys 32-63

    // ---- QK^T both halves up front ----
    f32x16 s0v = {}, s1v = {};
    __builtin_amdgcn_s_setprio(1);
    #pragma unroll
    for (int kk = 0; kk < 4; ++kk) {
      short8 ka = *(const short8*)(kbase0 + ((kk * 32 + hi * 16) ^ kswz));
      s0v = MFMA32(ka, bq[kk], s0v);
    }
    #pragma unroll
    for (int kk = 0; kk < 4; ++kk) {
      short8 ka = *(const short8*)(kbase1 + ((kk * 32 + hi * 16) ^ kswz));
      s1v = MFMA32(ka, bq[kk], s1v);
    }
    __builtin_amdgcn_s_setprio(0);

    #pragma unroll
    for (int kb = 0; kb < 2; ++kb) {
      const f32x16 s = kb ? s1v : s0v;

      // ---- softmax numerator: P = exp2(s), raw v_exp_f32 ----
      unsigned int pk_[8];
      float t0 = 0.f, t1 = 0.f;
      #pragma unroll
      for (int i = 0; i < 8; ++i) {
        const float pa = __builtin_amdgcn_exp2f(s[2 * i]);
        const float pb = __builtin_amdgcn_exp2f(s[2 * i + 1]);
        if (i & 1) t1 += pa + pb; else t0 += pa + pb;
        pk_[i] = pk2bf(pa, pb);
      }
      lsum += t0 + t1;   // per-lane partial; cross-lane reduce at epilogue

      // ---- build PV B-frags: 4 permlane32_swap ----
      const uint2v r02 = __builtin_amdgcn_permlane32_swap(pk_[0], pk_[2], false, false);
      const uint2v r13 = __builtin_amdgcn_permlane32_swap(pk_[1], pk_[3], false, false);
      const uint2v r46 = __builtin_amdgcn_permlane32_swap(pk_[4], pk_[6], false, false);
      const uint2v r57 = __builtin_amdgcn_permlane32_swap(pk_[5], pk_[7], false, false);
      uint4v b0v, b1v;
      b0v[0] = r02[0]; b0v[1] = r13[0]; b0v[2] = r02[1]; b0v[3] = r13[1];
      b1v[0] = r46[0]; b1v[1] = r57[0]; b1v[2] = r46[1]; b1v[3] = r57[1];
      const short8 pb0 = __builtin_bit_cast(short8, b0v);
      const short8 pb1 = __builtin_bit_cast(short8, b1v);

      // ---- O^T += V^T P^T (A = V^T[d][16 keys], B = P[16 keys][q]) ----
      __builtin_amdgcn_s_setprio(1);
      #pragma unroll
      for (int kk = 0; kk < 2; ++kk) {
        const short8 pbk = kk ? pb1 : pb0;
        const int koff = kb * 64 + kk * 32 + hi * 16;
        short8 va0 = *(const short8*)(Vb + l31 * 128 + (koff ^ vswz));
        o0 = MFMA32(va0, pbk, o0);
        short8 va1 = *(const short8*)(Vb + (32 + l31) * 128 + (koff ^ vswz));
        o1 = MFMA32(va1, pbk, o1);
      }
      __builtin_amdgcn_s_setprio(0);
    }

    // rotate buffers: no end-of-iter barrier needed (3-buf hazard analysis)
    const int bt = bc; bc = bn; bn = 3 - bt - bn;  // (bc,bn) -> (bn, third)
  }

  // ---- epilogue: single cross-lane lsum reduce, lane-local normalize ----
  lsum += __shfl_xor(lsum, 32);
  const float inv = 1.f / lsum;
  unsigned short* aop = AO + ((size_t)(b_ * 1024 + q0 + l31)) * 768 + h * 64;
  #pragma unroll
  for (int g = 0; g < 4; ++g) {
    uint2v s0, s1;
    s0[0] = pk2bf(o0[4 * g] * inv,     o0[4 * g + 1] * inv);
    s0[1] = pk2bf(o0[4 * g + 2] * inv, o0[4 * g + 3] * inv);
    *(uint2v*)(aop + g * 8 + 4 * hi) = s0;
    s1[0] = pk2bf(o1[4 * g] * inv,     o1[4 * g + 1] * inv);
    s1[1] = pk2bf(o1[4 * g + 2] * inv, o1[4 * g + 3] * inv);
    *(uint2v*)(aop + 32 + g * 8 + 4 * hi) = s1;
  }
}

// ---------------------------------------------------------------------------
extern "C" void kernel_launch(void* const* d_in, const int* in_sizes, int n_in,
                              void* d_out, int out_size, void* d_ws, size_t ws_size,
                              hipStream_t stream)
{
  const float* x      = (const float*)d_in[0];
  const float* qkv_w  = (const float*)d_in[1];
  const float* qkv_b  = (const float*)d_in[2];
  const float* proj_w = (const float*)d_in[3];
  const float* proj_b = (const float*)d_in[4];
  float* out = (float*)d_out;

  // ws (bf16 elems): [xb|AO] | Qt | Kt | Vt | qkv_wb | proj_wb  = 55.05 MB
  unsigned short* ws = (unsigned short*)d_ws;
  unsigned short* xb  = ws;                  // x as bf16; dead after QKV gemm
  unsigned short* Qt  = ws + 6291456;
  unsigned short* Kt  = Qt + 6291456;
  unsigned short* Vt  = Kt + 6291456;
  unsigned short* qwb = Vt + 6291456;        // 2304x768 bf16
  unsigned short* pwb = qwb + 1769472;       // 768x768 bf16
  unsigned short* AO  = xb;                  // reuse (disjoint lifetime)

  cvt3<<<8448, 256, 0, stream>>>(x, xb, 1572864, qkv_w, qwb, 442368, proj_w, pwb);
  gemm_bt<0><<<dim3(64, 18), 256, 0, stream>>>(xb, qwb, qkv_b, Qt, Kt, Vt, nullptr);
  attn_fwd<<<768, 256, 0, stream>>>(Qt, Kt, Vt, AO);
  gemm_bt<1><<<dim3(64, 6), 256, 0, stream>>>(AO, pwb, proj_b, nullptr, nullptr, nullptr, out);
}